// Round 1
// baseline (1637.344 us; speedup 1.0000x reference)
//
#include <hip/hip_runtime.h>

#define NODES 100000
#define HD 128
#define MSG 640   // 5 * HD

// Pass 1: per-node event counts (scatter_mean denominators).
__global__ void tgn_count_kernel(const int* __restrict__ src_ids,
                                 const int* __restrict__ dst_ids,
                                 int* __restrict__ cnt_src,
                                 int* __restrict__ cnt_dst,
                                 int L) {
    int i = blockIdx.x * blockDim.x + threadIdx.x;
    if (i < L) {
        atomicAdd(&cnt_src[src_ids[i]], 1);
        atomicAdd(&cnt_dst[dst_ids[i]], 1);
    }
}

// Pass 2: build both 640-dim messages per event and atomically accumulate
// the pre-scaled (by 1/count) contributions into out[(2, NODES, 640)].
// 128 threads per event: thread h handles dim h of every segment.
__global__ void tgn_message_kernel(const int* __restrict__ event_type_ids,
                                   const int* __restrict__ src_ids,
                                   const float* __restrict__ src_mask,
                                   const int* __restrict__ dst_ids,
                                   const float* __restrict__ dst_mask,
                                   const float* __restrict__ event_embeddings,
                                   const float* __restrict__ event_mask,
                                   const float* __restrict__ event_timestamps,
                                   const float* __restrict__ memory,
                                   const float* __restrict__ last_update,
                                   const float* __restrict__ time_w,
                                   const float* __restrict__ time_b,
                                   const int* __restrict__ cnt_src,
                                   const int* __restrict__ cnt_dst,
                                   float* __restrict__ out,
                                   int L) {
    long long idx = (long long)blockIdx.x * blockDim.x + threadIdx.x;
    int i = (int)(idx >> 7);   // event index
    int h = (int)(idx & 127);  // hidden dim
    if (i >= L) return;

    int s = src_ids[i];
    int d = dst_ids[i];
    float sm = src_mask[i];
    float dm = dst_mask[i];
    float em = event_mask[i];
    float ts = event_timestamps[i];
    float typ = (float)event_type_ids[i];

    float lus = last_update[s];
    float lud = last_update[d];
    float w = time_w[h];
    float b = time_b[h];

    float mem_s = memory[(size_t)s * HD + h] * sm;
    float mem_d = memory[(size_t)d * HD + h] * dm;
    // faithful quirk: both time deltas use dst_mask on last_update
    float ts_s = __cosf((ts - lus * dm) * w + b);
    float ts_d = __cosf((ts - lud * dm) * w + b);
    float emb = event_embeddings[(size_t)i * HD + h];

    float inv_cs = 1.0f / (float)max(cnt_src[s], 1);
    float inv_cd = 1.0f / (float)max(cnt_dst[d], 1);
    float esc = em * inv_cs;  // src message scale (event_mask / count_src)
    float dsc = dm * inv_cd;  // dst message scale (dst_mask / count_dst)

    float* os = out + (size_t)s * MSG;
    atomicAdd(os + 0 * HD + h, typ * esc);
    atomicAdd(os + 1 * HD + h, mem_s * esc);
    atomicAdd(os + 2 * HD + h, mem_d * esc);
    atomicAdd(os + 3 * HD + h, ts_s * esc);
    atomicAdd(os + 4 * HD + h, emb * esc);

    float* od = out + ((size_t)NODES + d) * MSG;
    atomicAdd(od + 0 * HD + h, typ * dsc);
    atomicAdd(od + 1 * HD + h, mem_d * dsc);
    atomicAdd(od + 2 * HD + h, mem_s * dsc);
    atomicAdd(od + 3 * HD + h, ts_d * dsc);
    atomicAdd(od + 4 * HD + h, emb * dsc);
}

extern "C" void kernel_launch(void* const* d_in, const int* in_sizes, int n_in,
                              void* d_out, int out_size, void* d_ws, size_t ws_size,
                              hipStream_t stream) {
    const int* event_type_ids = (const int*)d_in[0];
    const int* src_ids = (const int*)d_in[1];
    const float* src_mask = (const float*)d_in[2];
    const int* dst_ids = (const int*)d_in[3];
    const float* dst_mask = (const float*)d_in[4];
    const float* event_embeddings = (const float*)d_in[5];
    const float* event_mask = (const float*)d_in[6];
    const float* event_timestamps = (const float*)d_in[7];
    const float* memory = (const float*)d_in[8];
    const float* last_update = (const float*)d_in[9];
    const float* time_w = (const float*)d_in[10];
    const float* time_b = (const float*)d_in[11];

    int L = in_sizes[0];
    float* out = (float*)d_out;
    int* cnt_src = (int*)d_ws;
    int* cnt_dst = cnt_src + NODES;

    // Zero output sums (poisoned 0xAA each call) and counts.
    hipMemsetAsync(d_out, 0, (size_t)out_size * sizeof(float), stream);
    hipMemsetAsync(d_ws, 0, (size_t)2 * NODES * sizeof(int), stream);

    // Pass 1: counts.
    {
        int threads = 256;
        int blocks = (L + threads - 1) / threads;
        tgn_count_kernel<<<blocks, threads, 0, stream>>>(src_ids, dst_ids,
                                                         cnt_src, cnt_dst, L);
    }

    // Pass 2: messages + scaled scatter-add.
    {
        int threads = 256;
        long long total = (long long)L * HD;
        int blocks = (int)((total + threads - 1) / threads);
        tgn_message_kernel<<<blocks, threads, 0, stream>>>(
            event_type_ids, src_ids, src_mask, dst_ids, dst_mask,
            event_embeddings, event_mask, event_timestamps,
            memory, last_update, time_w, time_b,
            cnt_src, cnt_dst, out, L);
    }
}

// Round 2
// 841.651 us; speedup vs baseline: 1.9454x; 1.9454x over previous
//
#include <hip/hip_runtime.h>

#define NODES 100000
#define HD 128
#define MSG 640   // 5 * HD
#define NS (2 * NODES)  // node-sides: [0,NODES)=src rows, [NODES,2*NODES)=dst rows

// Workspace layout (ints):
//   cnt[NS]      : per node-side event count        (needs zeroing)
//   gcur[1]      : global allocation cursor         (needs zeroing)
//   off[NS]      : per node-side list start
//   cursor[NS]   : fill cursors (copy of off)
//   list[2L]     : event indices, bucketed by node-side

// Pass 1: per-node-side event counts.
__global__ void tgn_count_kernel(const int* __restrict__ src_ids,
                                 const int* __restrict__ dst_ids,
                                 int* __restrict__ cnt, int L) {
    int i = blockIdx.x * blockDim.x + threadIdx.x;
    if (i < L) {
        atomicAdd(&cnt[src_ids[i]], 1);
        atomicAdd(&cnt[NODES + dst_ids[i]], 1);
    }
}

// Pass 2: allocate contiguous regions per node-side (order irrelevant).
// Wave-level exclusive scan + one atomic per wave (avoids 200k serialized
// atomics on one address).
__global__ void tgn_alloc_kernel(const int* __restrict__ cnt,
                                 int* __restrict__ off,
                                 int* __restrict__ cursor,
                                 int* __restrict__ gcur, int n) {
    int i = blockIdx.x * blockDim.x + threadIdx.x;
    int lane = threadIdx.x & 63;
    int c = (i < n) ? cnt[i] : 0;
    int p = c;
    #pragma unroll
    for (int o = 1; o < 64; o <<= 1) {
        int t = __shfl_up(p, o);
        if (lane >= o) p += t;
    }
    int total = __shfl(p, 63);
    int base = 0;
    if (lane == 63) base = atomicAdd(gcur, total);
    base = __shfl(base, 63);
    if (i < n) {
        int o = base + p - c;  // exclusive prefix
        off[i] = o;
        cursor[i] = o;
    }
}

// Pass 3: fill the bucketed event lists.
__global__ void tgn_fill_kernel(const int* __restrict__ src_ids,
                                const int* __restrict__ dst_ids,
                                int* __restrict__ cursor,
                                int* __restrict__ list, int L) {
    int i = blockIdx.x * blockDim.x + threadIdx.x;
    if (i < L) {
        int ps = atomicAdd(&cursor[src_ids[i]], 1);
        list[ps] = i;
        int pd = atomicAdd(&cursor[NODES + dst_ids[i]], 1);
        list[pd] = i;
    }
}

// Pass 4: one wave (64 lanes) per node-side row. Accumulate all of the row's
// events in registers, then one coalesced non-temporal store of 640 floats.
// Lane l owns dims {l, l+64} of each 128-wide segment.
__global__ __launch_bounds__(256) void tgn_node_kernel(
        const int* __restrict__ event_type_ids,
        const int* __restrict__ src_ids,
        const float* __restrict__ src_mask,
        const int* __restrict__ dst_ids,
        const float* __restrict__ dst_mask,
        const float* __restrict__ event_embeddings,
        const float* __restrict__ event_mask,
        const float* __restrict__ event_timestamps,
        const float* __restrict__ memory,
        const float* __restrict__ last_update,
        const float* __restrict__ time_w,
        const float* __restrict__ time_b,
        const int* __restrict__ cnt,
        const int* __restrict__ off,
        const int* __restrict__ list,
        float* __restrict__ out) {
    int wid = (int)((blockIdx.x * (long long)blockDim.x + threadIdx.x) >> 6);
    int lane = threadIdx.x & 63;
    if (wid >= NS) return;

    bool is_src = wid < NODES;
    int node = is_src ? wid : wid - NODES;
    int c = cnt[wid];
    int o = off[wid];

    float w0 = time_w[lane], w1 = time_w[lane + 64];
    float b0 = time_b[lane], b1 = time_b[lane + 64];
    // Loop-invariant: this node's own memory row and last_update.
    float self_m0 = memory[(size_t)node * HD + lane];
    float self_m1 = memory[(size_t)node * HD + lane + 64];
    float lu_self = last_update[node];

    float a_typ = 0.f;                       // seg 0 (same value both halves)
    float a_s0 = 0.f, a_s1 = 0.f;            // seg 1: self memory
    float a_o0 = 0.f, a_o1 = 0.f;            // seg 2: other memory
    float a_t0 = 0.f, a_t1 = 0.f;            // seg 3: time encoding
    float a_e0 = 0.f, a_e1 = 0.f;            // seg 4: event embedding

    for (int j = 0; j < c; ++j) {
        int e = list[o + j];
        int s = src_ids[e];
        int d = dst_ids[e];
        float sm = src_mask[e];
        float dm = dst_mask[e];
        float em = event_mask[e];
        float ts = event_timestamps[e];
        float typ = (float)event_type_ids[e];

        int other = is_src ? d : s;
        float scale = is_src ? em : dm;        // message mask
        float self_mask = is_src ? sm : dm;    // mask on own memory segment
        float other_mask = is_src ? dm : sm;   // mask on other memory segment

        float om0 = memory[(size_t)other * HD + lane] * other_mask;
        float om1 = memory[(size_t)other * HD + lane + 64] * other_mask;
        // faithful quirk: last_update always multiplied by dst_mask
        float tphase = ts - lu_self * dm;
        float t0 = __cosf(tphase * w0 + b0);
        float t1 = __cosf(tphase * w1 + b1);
        float e0 = event_embeddings[(size_t)e * HD + lane];
        float e1 = event_embeddings[(size_t)e * HD + lane + 64];

        a_typ += typ * scale;
        a_s0 += self_m0 * self_mask * scale;
        a_s1 += self_m1 * self_mask * scale;
        a_o0 += om0 * scale;
        a_o1 += om1 * scale;
        a_t0 += t0 * scale;
        a_t1 += t1 * scale;
        a_e0 += e0 * scale;
        a_e1 += e1 * scale;
    }

    float inv = (c > 0) ? (1.0f / (float)c) : 0.0f;
    float* row = out + (size_t)wid * MSG;
    __builtin_nontemporal_store(a_typ * inv, row + 0 * HD + lane);
    __builtin_nontemporal_store(a_typ * inv, row + 0 * HD + lane + 64);
    __builtin_nontemporal_store(a_s0 * inv, row + 1 * HD + lane);
    __builtin_nontemporal_store(a_s1 * inv, row + 1 * HD + lane + 64);
    __builtin_nontemporal_store(a_o0 * inv, row + 2 * HD + lane);
    __builtin_nontemporal_store(a_o1 * inv, row + 2 * HD + lane + 64);
    __builtin_nontemporal_store(a_t0 * inv, row + 3 * HD + lane);
    __builtin_nontemporal_store(a_t1 * inv, row + 3 * HD + lane + 64);
    __builtin_nontemporal_store(a_e0 * inv, row + 4 * HD + lane);
    __builtin_nontemporal_store(a_e1 * inv, row + 4 * HD + lane + 64);
}

extern "C" void kernel_launch(void* const* d_in, const int* in_sizes, int n_in,
                              void* d_out, int out_size, void* d_ws, size_t ws_size,
                              hipStream_t stream) {
    const int* event_type_ids = (const int*)d_in[0];
    const int* src_ids = (const int*)d_in[1];
    const float* src_mask = (const float*)d_in[2];
    const int* dst_ids = (const int*)d_in[3];
    const float* dst_mask = (const float*)d_in[4];
    const float* event_embeddings = (const float*)d_in[5];
    const float* event_mask = (const float*)d_in[6];
    const float* event_timestamps = (const float*)d_in[7];
    const float* memory = (const float*)d_in[8];
    const float* last_update = (const float*)d_in[9];
    const float* time_w = (const float*)d_in[10];
    const float* time_b = (const float*)d_in[11];

    int L = in_sizes[0];
    float* out = (float*)d_out;

    int* cnt = (int*)d_ws;        // [NS]
    int* gcur = cnt + NS;         // [1]
    int* off = gcur + 1;          // [NS]
    int* cursor = off + NS;       // [NS]
    int* list = cursor + NS;      // [2L]

    // Zero only cnt + gcur (off/cursor/list are fully overwritten).
    hipMemsetAsync(cnt, 0, (size_t)(NS + 1) * sizeof(int), stream);

    int threads = 256;
    tgn_count_kernel<<<(L + threads - 1) / threads, threads, 0, stream>>>(
        src_ids, dst_ids, cnt, L);

    tgn_alloc_kernel<<<(NS + threads - 1) / threads, threads, 0, stream>>>(
        cnt, off, cursor, gcur, NS);

    tgn_fill_kernel<<<(L + threads - 1) / threads, threads, 0, stream>>>(
        src_ids, dst_ids, cursor, list, L);

    long long total_threads = (long long)NS * 64;
    int blocks = (int)((total_threads + threads - 1) / threads);
    tgn_node_kernel<<<blocks, threads, 0, stream>>>(
        event_type_ids, src_ids, src_mask, dst_ids, dst_mask,
        event_embeddings, event_mask, event_timestamps,
        memory, last_update, time_w, time_b,
        cnt, off, list, out);
}